// Round 2
// baseline (39.958 us; speedup 1.0000x reference)
//
#include <hip/hip_runtime.h>
#include <math.h>

// NCM classifier: B=1024 samples, C=500 classes, F=512 features (all fp32).
//   xs = x / variance[0]
//   dist[b][c] = sqrt(sum_f (xs[b][f] - means[c][f])^2)
//   out = concat(softmax(-dist, axis=1), -dist, dist)   // each [B][C]
#define NB 1024
#define NC 500
#define NF 512

// Distance kernel tiling: 64 (b) x 32 (c) block tile, 256 threads, each
// thread computes a 4x2 micro-tile. grid = (1024/64) x ceil(500/32) = 16x16
// = 256 blocks -> exactly 1 block per CU (all CUs busy).
#define BM 64
#define BN 32
#define KF 32
#define LSTRIDE (KF + 4)  // 36 floats: 16B-aligned rows, banks spread (36%32=4)

__global__ __launch_bounds__(256) void ncm_dist_kernel(
    const float* __restrict__ x, const float* __restrict__ means,
    const float* __restrict__ variance, float* __restrict__ out)
{
    __shared__ float sx[BM * LSTRIDE];  // 64 x 36 floats = 9216 B
    __shared__ float sm[BN * LSTRIDE];  // 32 x 36 floats = 4608 B

    const int t  = threadIdx.x;
    const int tx = t & 15;   // c direction (2 cols: tx, tx+16)
    const int ty = t >> 4;   // b direction (4 rows: ty + i*16)

    const int b0 = blockIdx.x * BM;
    const int c0 = blockIdx.y * BN;

    const float var = variance[0];

    float acc[4][2];
    #pragma unroll
    for (int i = 0; i < 4; ++i)
        #pragma unroll
        for (int j = 0; j < 2; ++j) acc[i][j] = 0.0f;

    // staging indices: float4 granularity
    const int srow = t >> 3;        // 0..31
    const int scol = (t & 7) << 2;  // 0,4,...,28

    for (int f0 = 0; f0 < NF; f0 += KF) {
        __syncthreads();  // protect previous tile from overwrite
        // x tile: 64 rows x 32 floats = 512 float4 -> 2 per thread
        #pragma unroll
        for (int k = 0; k < 2; ++k) {
            int r = srow + 32 * k;
            float4 v = *reinterpret_cast<const float4*>(
                &x[(size_t)(b0 + r) * NF + f0 + scol]);
            v.x /= var; v.y /= var; v.z /= var; v.w /= var;
            *reinterpret_cast<float4*>(&sx[r * LSTRIDE + scol]) = v;
        }
        // means tile: 32 rows x 32 floats = 256 float4 -> 1 per thread
        {
            int c = c0 + srow;
            float4 v;
            if (c < NC)
                v = *reinterpret_cast<const float4*>(
                    &means[(size_t)c * NF + f0 + scol]);
            else
                v = make_float4(0.f, 0.f, 0.f, 0.f);
            *reinterpret_cast<float4*>(&sm[srow * LSTRIDE + scol]) = v;
        }
        __syncthreads();

        #pragma unroll
        for (int f4 = 0; f4 < KF / 4; ++f4) {
            float4 xv[4], mv[2];
            #pragma unroll
            for (int i = 0; i < 4; ++i)
                xv[i] = *reinterpret_cast<const float4*>(
                    &sx[(ty + i * 16) * LSTRIDE + f4 * 4]);
            #pragma unroll
            for (int j = 0; j < 2; ++j)
                mv[j] = *reinterpret_cast<const float4*>(
                    &sm[(tx + j * 16) * LSTRIDE + f4 * 4]);
            #pragma unroll
            for (int i = 0; i < 4; ++i)
                #pragma unroll
                for (int j = 0; j < 2; ++j) {
                    float d0 = xv[i].x - mv[j].x;
                    float d1 = xv[i].y - mv[j].y;
                    float d2 = xv[i].z - mv[j].z;
                    float d3 = xv[i].w - mv[j].w;
                    acc[i][j] += d0 * d0;
                    acc[i][j] += d1 * d1;
                    acc[i][j] += d2 * d2;
                    acc[i][j] += d3 * d3;
                }
        }
    }

    float* expo  = out + (size_t)NB * NC;
    float* cdiff = out + (size_t)2 * NB * NC;
    #pragma unroll
    for (int i = 0; i < 4; ++i) {
        int b = b0 + ty + i * 16;
        #pragma unroll
        for (int j = 0; j < 2; ++j) {
            int c = c0 + tx + j * 16;
            if (c < NC) {
                float d = sqrtf(acc[i][j]);
                expo[(size_t)b * NC + c]  = -d;
                cdiff[(size_t)b * NC + c] = d;
            }
        }
    }
}

// Row softmax over C=500: one block (256 threads = 4 waves) per row.
__global__ __launch_bounds__(256) void ncm_softmax_kernel(float* __restrict__ out)
{
    __shared__ float redm[4];
    __shared__ float reds[4];
    const int b = blockIdx.x;
    const float* expo = out + (size_t)NB * NC + (size_t)b * NC;
    float* probs = out + (size_t)b * NC;
    const int t = threadIdx.x;

    float v0 = (t < NC) ? expo[t] : -1e30f;
    float v1 = (t + 256 < NC) ? expo[t + 256] : -1e30f;

    float m = fmaxf(v0, v1);
    #pragma unroll
    for (int off = 32; off > 0; off >>= 1)
        m = fmaxf(m, __shfl_down(m, off, 64));
    if ((t & 63) == 0) redm[t >> 6] = m;
    __syncthreads();
    float mall = fmaxf(fmaxf(redm[0], redm[1]), fmaxf(redm[2], redm[3]));

    float e0 = (t < NC) ? expf(v0 - mall) : 0.0f;
    float e1 = (t + 256 < NC) ? expf(v1 - mall) : 0.0f;
    float s = e0 + e1;
    #pragma unroll
    for (int off = 32; off > 0; off >>= 1)
        s += __shfl_down(s, off, 64);
    if ((t & 63) == 0) reds[t >> 6] = s;
    __syncthreads();
    float sall = reds[0] + reds[1] + reds[2] + reds[3];
    float inv = 1.0f / sall;

    if (t < NC) probs[t] = e0 * inv;
    if (t + 256 < NC) probs[t + 256] = e1 * inv;
}

extern "C" void kernel_launch(void* const* d_in, const int* in_sizes, int n_in,
                              void* d_out, int out_size, void* d_ws, size_t ws_size,
                              hipStream_t stream) {
    const float* x        = (const float*)d_in[0];
    const float* means    = (const float*)d_in[1];
    const float* variance = (const float*)d_in[2];
    float* out = (float*)d_out;

    dim3 g1(NB / BM, (NC + BN - 1) / BN);  // (16, 16) = 256 blocks
    ncm_dist_kernel<<<g1, 256, 0, stream>>>(x, means, variance, out);
    ncm_softmax_kernel<<<NB, 256, 0, stream>>>(out);
}

// Round 3
// 23.748 us; speedup vs baseline: 1.6826x; 1.6826x over previous
//
#include <hip/hip_runtime.h>
#include <math.h>

// NCM classifier: B=1024 samples, C=500 classes, F=512 features (fp32 in/out).
//   xs = x / variance[0]
//   dist[b][c] = sqrt(sum_f (xs[b][f] - means[c][f])^2)
//   out = concat(softmax(-dist, axis=1), -dist, dist)   // each [B][C]
//
// Strategy: dist^2 = ||xs_b||^2 + ||m_c||^2 - 2 * (xs . m)  -> bf16 MFMA GEMM
// for the cross term (K=512), exact fp32 norms. Inputs are 1.5MB as bf16 ->
// fully L2-resident, so the GEMM loads fragments straight from global (no LDS).
#define NB 1024
#define NC 500
#define NCP 512   // padded classes
#define NF 512

typedef __attribute__((ext_vector_type(8))) short bf16x8;
typedef __attribute__((ext_vector_type(4))) float f32x4;

static __device__ inline ushort f2bf(float f) {
    union { float f; uint u; } v; v.f = f;
    uint u = v.u;
    return (ushort)((u + 0x7fffu + ((u >> 16) & 1u)) >> 16);  // RNE
}

// ---------------- prep: fp32 -> bf16 + row norms ----------------
// One wave per row. Rows 0..1023 = x (scaled by 1/var), rows 1024..1535 =
// means (rows >= NC zero-filled). 256 threads = 4 rows per block.
__global__ __launch_bounds__(256) void ncm_prep_kernel(
    const float* __restrict__ x, const float* __restrict__ means,
    const float* __restrict__ variance,
    ushort* __restrict__ xb, ushort* __restrict__ mb,
    float* __restrict__ nx, float* __restrict__ nm)
{
    const int t    = threadIdx.x;
    const int lane = t & 63;
    const int row  = blockIdx.x * 4 + (t >> 6);
    const float inv_var = 1.0f / variance[0];

    const float* src;
    ushort* dst;
    float* nrm;
    float scale;
    bool zero = false;
    if (row < NB) {
        src = x + (size_t)row * NF;       dst = xb + (size_t)row * NF;
        nrm = nx + row;                   scale = inv_var;
    } else {
        int c = row - NB;
        src = means + (size_t)c * NF;     dst = mb + (size_t)c * NF;
        nrm = nm + c;                     scale = 1.0f;
        zero = (c >= NC);
    }

    float4 v0, v1;
    if (!zero) {
        v0 = *reinterpret_cast<const float4*>(&src[lane * 8]);
        v1 = *reinterpret_cast<const float4*>(&src[lane * 8 + 4]);
        v0.x *= scale; v0.y *= scale; v0.z *= scale; v0.w *= scale;
        v1.x *= scale; v1.y *= scale; v1.z *= scale; v1.w *= scale;
    } else {
        v0 = make_float4(0.f, 0.f, 0.f, 0.f);
        v1 = v0;
    }

    uint4 o;
    o.x = (uint)f2bf(v0.x) | ((uint)f2bf(v0.y) << 16);
    o.y = (uint)f2bf(v0.z) | ((uint)f2bf(v0.w) << 16);
    o.z = (uint)f2bf(v1.x) | ((uint)f2bf(v1.y) << 16);
    o.w = (uint)f2bf(v1.z) | ((uint)f2bf(v1.w) << 16);
    *reinterpret_cast<uint4*>(&dst[lane * 8]) = o;

    float s = v0.x * v0.x + v0.y * v0.y + v0.z * v0.z + v0.w * v0.w
            + v1.x * v1.x + v1.y * v1.y + v1.z * v1.z + v1.w * v1.w;
    #pragma unroll
    for (int off = 32; off > 0; off >>= 1) s += __shfl_xor(s, off, 64);
    if (lane == 0) *nrm = s;
}

// ---------------- GEMM + distance epilogue ----------------
// One wave per block, 32x32 output tile (2x2 fragments of 16x16x32 bf16).
// grid = (1024/32, 512/32) = (32, 16) = 512 blocks -> 2 waves/CU, no barriers.
// A (xs) and B^T (means) both read 16B contiguous along K per lane.
__global__ __launch_bounds__(64) void ncm_gemm_kernel(
    const ushort* __restrict__ xb, const ushort* __restrict__ mb,
    const float* __restrict__ nx, const float* __restrict__ nm,
    float* __restrict__ out)
{
    const int lane = threadIdx.x;
    const int b0 = blockIdx.x * 32;
    const int c0 = blockIdx.y * 32;

    const int fr = lane & 15;         // fragment row/col within 16
    const int kg = (lane >> 4) * 8;   // k-group offset (0,8,16,24)

    const ushort* aptr0 = xb + (size_t)(b0 + fr) * NF + kg;
    const ushort* aptr1 = aptr0 + (size_t)16 * NF;
    const ushort* bptr0 = mb + (size_t)(c0 + fr) * NF + kg;
    const ushort* bptr1 = bptr0 + (size_t)16 * NF;

    f32x4 acc00 = {0.f, 0.f, 0.f, 0.f};
    f32x4 acc01 = acc00, acc10 = acc00, acc11 = acc00;

    #pragma unroll 4
    for (int k = 0; k < NF; k += 32) {
        bf16x8 a0 = *reinterpret_cast<const bf16x8*>(aptr0 + k);
        bf16x8 a1 = *reinterpret_cast<const bf16x8*>(aptr1 + k);
        bf16x8 bb0 = *reinterpret_cast<const bf16x8*>(bptr0 + k);
        bf16x8 bb1 = *reinterpret_cast<const bf16x8*>(bptr1 + k);
        acc00 = __builtin_amdgcn_mfma_f32_16x16x32_bf16(a0, bb0, acc00, 0, 0, 0);
        acc01 = __builtin_amdgcn_mfma_f32_16x16x32_bf16(a0, bb1, acc01, 0, 0, 0);
        acc10 = __builtin_amdgcn_mfma_f32_16x16x32_bf16(a1, bb0, acc10, 0, 0, 0);
        acc11 = __builtin_amdgcn_mfma_f32_16x16x32_bf16(a1, bb1, acc11, 0, 0, 0);
    }

    // C/D layout (m89/m91): col = lane&15, row = (lane>>4)*4 + reg
    float* expo  = out + (size_t)NB * NC;
    float* cdiff = out + (size_t)2 * NB * NC;
    const int rg = (lane >> 4) * 4;
    const int c_lo = c0 + fr;        // wn = 0
    const int c_hi = c_lo + 16;      // wn = 1
    const float nm_lo = nm[c_lo];
    const float nm_hi = nm[c_hi];

    #pragma unroll
    for (int wm = 0; wm < 2; ++wm) {
        f32x4 g_lo = wm ? acc10 : acc00;
        f32x4 g_hi = wm ? acc11 : acc01;
        #pragma unroll
        for (int r = 0; r < 4; ++r) {
            int b = b0 + wm * 16 + rg + r;
            float nxb = nx[b];
            if (c_lo < NC) {
                float d2 = nxb + nm_lo - 2.0f * g_lo[r];
                float d = sqrtf(fmaxf(d2, 0.0f));
                expo[(size_t)b * NC + c_lo]  = -d;
                cdiff[(size_t)b * NC + c_lo] = d;
            }
            if (c_hi < NC) {
                float d2 = nxb + nm_hi - 2.0f * g_hi[r];
                float d = sqrtf(fmaxf(d2, 0.0f));
                expo[(size_t)b * NC + c_hi]  = -d;
                cdiff[(size_t)b * NC + c_hi] = d;
            }
        }
    }
}

// ---------------- fallback fp32 dist (correct, ~41us) ----------------
#define BM 64
#define BN 32
#define KF 32
#define LSTRIDE (KF + 4)

__global__ __launch_bounds__(256) void ncm_dist_kernel(
    const float* __restrict__ x, const float* __restrict__ means,
    const float* __restrict__ variance, float* __restrict__ out)
{
    __shared__ float sx[BM * LSTRIDE];
    __shared__ float sm[BN * LSTRIDE];

    const int t  = threadIdx.x;
    const int tx = t & 15;
    const int ty = t >> 4;
    const int b0 = blockIdx.x * BM;
    const int c0 = blockIdx.y * BN;
    const float var = variance[0];

    float acc[4][2];
    #pragma unroll
    for (int i = 0; i < 4; ++i)
        #pragma unroll
        for (int j = 0; j < 2; ++j) acc[i][j] = 0.0f;

    const int srow = t >> 3;
    const int scol = (t & 7) << 2;

    for (int f0 = 0; f0 < NF; f0 += KF) {
        __syncthreads();
        #pragma unroll
        for (int k = 0; k < 2; ++k) {
            int r = srow + 32 * k;
            float4 v = *reinterpret_cast<const float4*>(
                &x[(size_t)(b0 + r) * NF + f0 + scol]);
            v.x /= var; v.y /= var; v.z /= var; v.w /= var;
            *reinterpret_cast<float4*>(&sx[r * LSTRIDE + scol]) = v;
        }
        {
            int c = c0 + srow;
            float4 v;
            if (c < NC)
                v = *reinterpret_cast<const float4*>(
                    &means[(size_t)c * NF + f0 + scol]);
            else
                v = make_float4(0.f, 0.f, 0.f, 0.f);
            *reinterpret_cast<float4*>(&sm[srow * LSTRIDE + scol]) = v;
        }
        __syncthreads();

        #pragma unroll
        for (int f4 = 0; f4 < KF / 4; ++f4) {
            float4 xv[4], mv[2];
            #pragma unroll
            for (int i = 0; i < 4; ++i)
                xv[i] = *reinterpret_cast<const float4*>(
                    &sx[(ty + i * 16) * LSTRIDE + f4 * 4]);
            #pragma unroll
            for (int j = 0; j < 2; ++j)
                mv[j] = *reinterpret_cast<const float4*>(
                    &sm[(tx + j * 16) * LSTRIDE + f4 * 4]);
            #pragma unroll
            for (int i = 0; i < 4; ++i)
                #pragma unroll
                for (int j = 0; j < 2; ++j) {
                    float d0 = xv[i].x - mv[j].x;
                    float d1 = xv[i].y - mv[j].y;
                    float d2 = xv[i].z - mv[j].z;
                    float d3 = xv[i].w - mv[j].w;
                    acc[i][j] += d0 * d0 + d1 * d1 + d2 * d2 + d3 * d3;
                }
        }
    }

    float* expo  = out + (size_t)NB * NC;
    float* cdiff = out + (size_t)2 * NB * NC;
    #pragma unroll
    for (int i = 0; i < 4; ++i) {
        int b = b0 + ty + i * 16;
        #pragma unroll
        for (int j = 0; j < 2; ++j) {
            int c = c0 + tx + j * 16;
            if (c < NC) {
                float d = sqrtf(acc[i][j]);
                expo[(size_t)b * NC + c]  = -d;
                cdiff[(size_t)b * NC + c] = d;
            }
        }
    }
}

// ---------------- softmax over C=500, one block per row ----------------
__global__ __launch_bounds__(256) void ncm_softmax_kernel(float* __restrict__ out)
{
    __shared__ float redm[4];
    __shared__ float reds[4];
    const int b = blockIdx.x;
    const float* expo = out + (size_t)NB * NC + (size_t)b * NC;
    float* probs = out + (size_t)b * NC;
    const int t = threadIdx.x;

    float v0 = (t < NC) ? expo[t] : -1e30f;
    float v1 = (t + 256 < NC) ? expo[t + 256] : -1e30f;

    float m = fmaxf(v0, v1);
    #pragma unroll
    for (int off = 32; off > 0; off >>= 1)
        m = fmaxf(m, __shfl_down(m, off, 64));
    if ((t & 63) == 0) redm[t >> 6] = m;
    __syncthreads();
    float mall = fmaxf(fmaxf(redm[0], redm[1]), fmaxf(redm[2], redm[3]));

    float e0 = (t < NC) ? expf(v0 - mall) : 0.0f;
    float e1 = (t + 256 < NC) ? expf(v1 - mall) : 0.0f;
    float s = e0 + e1;
    #pragma unroll
    for (int off = 32; off > 0; off >>= 1)
        s += __shfl_down(s, off, 64);
    if ((t & 63) == 0) reds[t >> 6] = s;
    __syncthreads();
    float sall = reds[0] + reds[1] + reds[2] + reds[3];
    float inv = 1.0f / sall;

    if (t < NC) probs[t] = e0 * inv;
    if (t + 256 < NC) probs[t + 256] = e1 * inv;
}

extern "C" void kernel_launch(void* const* d_in, const int* in_sizes, int n_in,
                              void* d_out, int out_size, void* d_ws, size_t ws_size,
                              hipStream_t stream) {
    const float* x        = (const float*)d_in[0];
    const float* means    = (const float*)d_in[1];
    const float* variance = (const float*)d_in[2];
    float* out = (float*)d_out;

    // workspace layout: xb [1024*512 bf16] | mb [512*512 bf16] | nm[512] | nx[1024]
    const size_t xb_elems = (size_t)NB * NF;
    const size_t mb_elems = (size_t)NCP * NF;
    const size_t need = xb_elems * 2 + mb_elems * 2 + NCP * 4 + NB * 4;

    if (ws_size >= need) {
        ushort* xb = (ushort*)d_ws;
        ushort* mb = xb + xb_elems;
        float* nm = (float*)(mb + mb_elems);
        float* nx = nm + NCP;

        ncm_prep_kernel<<<(NB + NCP) / 4, 256, 0, stream>>>(
            x, means, variance, xb, mb, nx, nm);
        dim3 g(NB / 32, NCP / 32);  // (32, 16) = 512 single-wave blocks
        ncm_gemm_kernel<<<g, 64, 0, stream>>>(xb, mb, nx, nm, out);
    } else {
        dim3 g1(NB / BM, (NC + BN - 1) / BN);
        ncm_dist_kernel<<<g1, 256, 0, stream>>>(x, means, variance, out);
    }
    ncm_softmax_kernel<<<NB, 256, 0, stream>>>(out);
}